// Round 4
// baseline (190.781 us; speedup 1.0000x reference)
//
#include <hip/hip_runtime.h>

#define NROWS  32768
#define DIM    64
#define KCODES 1024
#define NELEM  (NROWS * DIM)   // 2097152
#define CHUNKS 32
#define CPC    (KCODES / CHUNKS)   // 32 codes per chunk-block

typedef float v2f __attribute__((ext_vector_type(2)));

// numpy-style pairwise sum of squares for n=64 contiguous fp32 (contraction
// OFF so the squared temps are not fused into the adds; matches jnp.sum(x*x)).
// Verified absmax 0.0 in all prior rounds.
__device__ __forceinline__ float np_sumsq64(const float v[64]) {
#pragma clang fp contract(off)
  float r0 = v[0] * v[0];
  float r1 = v[1] * v[1];
  float r2 = v[2] * v[2];
  float r3 = v[3] * v[3];
  float r4 = v[4] * v[4];
  float r5 = v[5] * v[5];
  float r6 = v[6] * v[6];
  float r7 = v[7] * v[7];
#pragma unroll
  for (int i = 8; i < 64; i += 8) {
    r0 += v[i + 0] * v[i + 0];
    r1 += v[i + 1] * v[i + 1];
    r2 += v[i + 2] * v[i + 2];
    r3 += v[i + 3] * v[i + 3];
    r4 += v[i + 4] * v[i + 4];
    r5 += v[i + 5] * v[i + 5];
    r6 += v[i + 6] * v[i + 6];
    r7 += v[i + 7] * v[i + 7];
  }
  return ((r0 + r1) + (r2 + r3)) + ((r4 + r5) + (r6 + r7));
}

// Init (grid 128x256): keys to +inf, cnt zero, per-code ||e||^2.
__global__ __launch_bounds__(256) void vq_init(const float* __restrict__ w,
                                               float* __restrict__ se,
                                               unsigned long long* __restrict__ keys,
                                               unsigned int* __restrict__ cnt) {
  const int t = blockIdx.x * 256 + threadIdx.x;  // 0..32767
  if (t == 0) *cnt = 0u;
  keys[t] = ~0ull;

  if (t < KCODES) {
    float v[64];
    const float4* wr = (const float4*)(w + (size_t)t * DIM);
#pragma unroll
    for (int i = 0; i < 16; ++i) {
      float4 q = wr[i];
      v[4 * i + 0] = q.x; v[4 * i + 1] = q.y;
      v[4 * i + 2] = q.z; v[4 * i + 3] = q.w;
    }
    se[t] = np_sumsq64(v);
  }
}

// Phase 2: distances + argmin, M=2 rows/thread, dual-feed w.
// Round-3 post-mortem: LDS broadcast alone is return-path-bound (~6 cyc per
// ds_read_b128 broadcast -> 17 reads/code saturate the per-CU LDS pipe at
// ~55-85us); round-1's scalar-only path stalls 44% because one code's w =
// 64 SGPRs and two don't fit the ~102-SGPR file (no double-buffering).
// Fix: (a) M=2 -> per code, same w bytes feed 2x FMA work (~300 VALU cyc),
// halving both feeds' relative cost; (b) split w per code: float4s 0..7 from
// LDS broadcast (8 reads ~ 50 LDS cyc < 300 VALU cyc across 4 waves/SIMD),
// float4s 8..15 from the scalar path (2 s_load_dwordx16 = 32 SGPRs -> room
// to prefetch). x: 2 rows = 128 floats in the unified VGPR/AGPR file
// (round-1/3 FETCH proves the compiler keeps such arrays resident).
// fp tree per row is op-for-op the verified sequence: a0..a3 accumulate over
// i=0,2,..,14 in order (loops split textually at i=8 only), then
// ((a0+a1)+(a2+a3)), dot=s.x+s.y, d=fma(-2,dot,fl(sx+se[c])); strict < over
// ascending c; u64 (dist_bits<<32)|c atomicMin merges chunks.
// Swizzle (dispatch round-robin over 256 CUs => same-CU blocks = bid mod 256
// fixed): group = bid&63 -> co-resident blocks share the SAME 512 rows (x
// HBM-fetched once, group pinned to XCD group&7); chunk = bid>>6.
__global__ __launch_bounds__(256, 2) void vq_dist(const float* __restrict__ x,
                                                  const float* __restrict__ w,
                                                  const float* __restrict__ se,
                                                  unsigned long long* __restrict__ keys) {
  __shared__ float wlo[CPC][32];   // low half (float4s 0..7) of each code, 4KB
  __shared__ float se_lds[CPC];
  const int b = blockIdx.x;
  const int group = b & 63;        // 0..63 (512 rows each)
  const int chunk = b >> 6;        // 0..31
  const int t = threadIdx.x;
  const int c0 = chunk * CPC;

  // Stage low halves: CPC*8 = 256 float4s, one per thread.
  {
    const float4* wsrc = (const float4*)w;
    float4* dst = (float4*)&wlo[0][0];
    const int c = t >> 3, j4 = t & 7;
    dst[t] = wsrc[(size_t)(c0 + c) * 16 + j4];
    if (t < CPC) se_lds[t] = se[c0 + t];
  }

  // Two rows resident in registers; sx via the exact verified tree.
  const int r0 = group * 512 + t;
  const int r1 = r0 + 256;
  float va[64], vb[64];
  {
    const float4* xr0 = (const float4*)(x + (size_t)r0 * DIM);
    const float4* xr1 = (const float4*)(x + (size_t)r1 * DIM);
#pragma unroll
    for (int i = 0; i < 16; ++i) {
      float4 qa = xr0[i];
      va[4 * i + 0] = qa.x; va[4 * i + 1] = qa.y;
      va[4 * i + 2] = qa.z; va[4 * i + 3] = qa.w;
      float4 qb = xr1[i];
      vb[4 * i + 0] = qb.x; vb[4 * i + 1] = qb.y;
      vb[4 * i + 2] = qb.z; vb[4 * i + 3] = qb.w;
    }
  }
  const float sxa = np_sumsq64(va);
  const float sxb = np_sumsq64(vb);

  __syncthreads();

  const float4* w4 = (const float4*)w;
  float bda = __builtin_inff(); int bca = 0;
  float bdb = __builtin_inff(); int bcb = 0;

#pragma unroll 2
  for (int j = 0; j < CPC; ++j) {
    const int c = c0 + j;
    const float4* wl = (const float4*)&wlo[j][0];       // LDS broadcast
    const float4* wh = w4 + (size_t)c * 16;             // uniform -> s_load
    v2f a0 = (v2f){0.f, 0.f}, a1 = (v2f){0.f, 0.f};
    v2f a2 = (v2f){0.f, 0.f}, a3 = (v2f){0.f, 0.f};
    v2f b0 = (v2f){0.f, 0.f}, b1 = (v2f){0.f, 0.f};
    v2f b2 = (v2f){0.f, 0.f}, b3 = (v2f){0.f, 0.f};
#pragma unroll
    for (int i = 0; i < 8; i += 2) {                    // float4s 0..7 (LDS)
      float4 t0 = wl[i];
      float4 t1 = wl[i + 1];
      a0 += (v2f){t0.x, t0.y} * (v2f){va[4 * i + 0], va[4 * i + 1]};
      a1 += (v2f){t0.z, t0.w} * (v2f){va[4 * i + 2], va[4 * i + 3]};
      a2 += (v2f){t1.x, t1.y} * (v2f){va[4 * i + 4], va[4 * i + 5]};
      a3 += (v2f){t1.z, t1.w} * (v2f){va[4 * i + 6], va[4 * i + 7]};
      b0 += (v2f){t0.x, t0.y} * (v2f){vb[4 * i + 0], vb[4 * i + 1]};
      b1 += (v2f){t0.z, t0.w} * (v2f){vb[4 * i + 2], vb[4 * i + 3]};
      b2 += (v2f){t1.x, t1.y} * (v2f){vb[4 * i + 4], vb[4 * i + 5]};
      b3 += (v2f){t1.z, t1.w} * (v2f){vb[4 * i + 6], vb[4 * i + 7]};
    }
#pragma unroll
    for (int i = 8; i < 16; i += 2) {                   // float4s 8..15 (SMEM)
      float4 t0 = wh[i];
      float4 t1 = wh[i + 1];
      a0 += (v2f){t0.x, t0.y} * (v2f){va[4 * i + 0], va[4 * i + 1]};
      a1 += (v2f){t0.z, t0.w} * (v2f){va[4 * i + 2], va[4 * i + 3]};
      a2 += (v2f){t1.x, t1.y} * (v2f){va[4 * i + 4], va[4 * i + 5]};
      a3 += (v2f){t1.z, t1.w} * (v2f){va[4 * i + 6], va[4 * i + 7]};
      b0 += (v2f){t0.x, t0.y} * (v2f){vb[4 * i + 0], vb[4 * i + 1]};
      b1 += (v2f){t0.z, t0.w} * (v2f){vb[4 * i + 2], vb[4 * i + 3]};
      b2 += (v2f){t1.x, t1.y} * (v2f){vb[4 * i + 4], vb[4 * i + 5]};
      b3 += (v2f){t1.z, t1.w} * (v2f){vb[4 * i + 6], vb[4 * i + 7]};
    }
    {
      v2f s01 = a0 + a1;
      v2f s23 = a2 + a3;
      v2f s = s01 + s23;
      float dot = s.x + s.y;
      float d = fmaf(-2.0f, dot, sxa + se_lds[j]);
      if (d < bda) { bda = d; bca = c; }
    }
    {
      v2f s01 = b0 + b1;
      v2f s23 = b2 + b3;
      v2f s = s01 + s23;
      float dot = s.x + s.y;
      float d = fmaf(-2.0f, dot, sxb + se_lds[j]);
      if (d < bdb) { bdb = d; bcb = c; }
    }
  }

  unsigned long long ka =
      ((unsigned long long)__float_as_uint(bda) << 32) | (unsigned long long)(unsigned)bca;
  unsigned long long kb =
      ((unsigned long long)__float_as_uint(bdb) << 32) | (unsigned long long)(unsigned)bcb;
  atomicMin(&keys[r0], ka);
  atomicMin(&keys[r1], kb);
}

// Phase 3 (grid 1024x256, 32 rows/block): decode key -> index, indices (as
// float), STE output x + fl(w - x), fp64 partial -> part[b] PLAIN STORE
// (round-3 lesson: the 1024-deep single-address f64 atomicAdd chain cost
// ~22us serialized). Last block (cnt) reduces the 1024 partials with
// device-scope atomic reads (cross-XCD coherence).
__global__ __launch_bounds__(256) void vq_out(const float* __restrict__ x,
                                              const float* __restrict__ w,
                                              const unsigned long long* __restrict__ keys,
                                              float* __restrict__ outq,
                                              float* __restrict__ outidx,
                                              double* __restrict__ part,
                                              unsigned int* __restrict__ cnt,
                                              float* __restrict__ outloss) {
  __shared__ int sidx[32];
  __shared__ double sp[4];
  __shared__ int lastf;
  const int b = blockIdx.x, t = threadIdx.x;

  if (t < 32) {
    const int row = b * 32 + t;
    unsigned long long k = keys[row];
    const int idx = (int)(unsigned int)(k & 0xFFFFFFFFull);
    outidx[row] = (float)idx;
    sidx[t] = idx;
  }
  __syncthreads();

  double acc = 0.0;
  const float4* x4 = (const float4*)x;
  float4* o4 = (float4*)outq;
#pragma unroll
  for (int i = 0; i < 2; ++i) {
    const int e = i * 256 + t;          // 0..511 float4s of this block's rows
    const int rl = e >> 4;              // local row (0..31)
    const int d4 = e & 15;              // float4 within the row
    const size_t gofs = ((size_t)b * 32 + rl) * 16 + d4;
    float4 xvv = x4[gofs];
    const float4* wr = (const float4*)(w + (size_t)sidx[rl] * DIM);
    float4 wv = wr[d4];
    float tx = wv.x - xvv.x, ty = wv.y - xvv.y;
    float tz = wv.z - xvv.z, tw = wv.w - xvv.w;
    float4 q;
    q.x = xvv.x + tx; q.y = xvv.y + ty;   // ref STE: x + fl(q - x)
    q.z = xvv.z + tz; q.w = xvv.w + tw;
    o4[gofs] = q;
    acc += (double)tx * tx + (double)ty * ty + (double)tz * tz + (double)tw * tw;
  }

#pragma unroll
  for (int s = 32; s > 0; s >>= 1) acc += __shfl_down(acc, s, 64);
  if ((t & 63) == 0) sp[t >> 6] = acc;
  __syncthreads();
  if (t == 0) {
    part[b] = (sp[0] + sp[1]) + (sp[2] + sp[3]);
    __threadfence();
    unsigned int old = atomicAdd(cnt, 1u);
    lastf = (old == 1023u) ? 1 : 0;
  }
  __syncthreads();

  if (lastf) {
    __threadfence();
    double a = 0.0;
#pragma unroll
    for (int i = 0; i < 4; ++i)
      a += atomicAdd(&part[t + 256 * i], 0.0);   // device-coherent read
#pragma unroll
    for (int s = 32; s > 0; s >>= 1) a += __shfl_down(a, s, 64);
    __syncthreads();                              // sp[] reuse
    if ((t & 63) == 0) sp[t >> 6] = a;
    __syncthreads();
    if (t == 0) {
      double total = (sp[0] + sp[1]) + (sp[2] + sp[3]);
      *outloss = 0.5f * (float)(total / (double)NELEM);
    }
  }
}

extern "C" void kernel_launch(void* const* d_in, const int* in_sizes, int n_in,
                              void* d_out, int out_size, void* d_ws, size_t ws_size,
                              hipStream_t stream) {
  const float* x = (const float*)d_in[0];   // inputs (32,64,32,32) fp32
  const float* w = (const float*)d_in[1];   // weight (1024,64) fp32

  float* outq    = (float*)d_out;           // [0, 2097152)
  float* outidx  = outq + NELEM;            // [2097152, +32768)
  float* outloss = outidx + NROWS;          // [2129920]

  char* wsb = (char*)d_ws;
  unsigned int* cnt = (unsigned int*)(wsb + 64);                    // 4 B
  float* se    = (float*)(wsb + 256);                               // 4 KB
  double* part = (double*)(wsb + 8192);                             // 8 KB
  unsigned long long* keys = (unsigned long long*)(wsb + 147456);   // 256 KB

  hipLaunchKernelGGL(vq_init, dim3(128),  dim3(256), 0, stream, w, se, keys, cnt);
  hipLaunchKernelGGL(vq_dist, dim3(2048), dim3(256), 0, stream, x, w, se, keys);
  hipLaunchKernelGGL(vq_out,  dim3(1024), dim3(256), 0, stream, x, w, keys, outq, outidx, part, cnt, outloss);
}

// Round 5
// 159.783 us; speedup vs baseline: 1.1940x; 1.1940x over previous
//
#include <hip/hip_runtime.h>

#define NROWS  32768
#define DIM    64
#define KCODES 1024
#define NELEM  (NROWS * DIM)   // 2097152
#define CHUNKS 8
#define CPC    (KCODES / CHUNKS)   // 128 codes per chunk-block
#define GROUPS 64                  // row-groups of 512 rows
#define GRID   (GROUPS * CHUNKS)   // 512 blocks = 2 blocks/CU

typedef float v2f __attribute__((ext_vector_type(2)));

// numpy-style pairwise sum of squares for n=64 contiguous fp32 (contraction
// OFF so squared temps are not fused into adds; matches jnp.sum(w*w)).
// Verified absmax 0.0 in all prior rounds. Used for se only (cold path).
__device__ __forceinline__ float np_sumsq64(const float v[64]) {
#pragma clang fp contract(off)
  float r0 = v[0] * v[0];
  float r1 = v[1] * v[1];
  float r2 = v[2] * v[2];
  float r3 = v[3] * v[3];
  float r4 = v[4] * v[4];
  float r5 = v[5] * v[5];
  float r6 = v[6] * v[6];
  float r7 = v[7] * v[7];
#pragma unroll
  for (int i = 8; i < 64; i += 8) {
    r0 += v[i + 0] * v[i + 0];
    r1 += v[i + 1] * v[i + 1];
    r2 += v[i + 2] * v[i + 2];
    r3 += v[i + 3] * v[i + 3];
    r4 += v[i + 4] * v[i + 4];
    r5 += v[i + 5] * v[i + 5];
    r6 += v[i + 6] * v[i + 6];
    r7 += v[i + 7] * v[i + 7];
  }
  return ((r0 + r1) + (r2 + r3)) + ((r4 + r5) + (r6 + r7));
}

// ONE fused kernel. Grid 512 = 64 row-groups x 8 K-chunks, 256 thr, M=2
// rows/thread (512 rows/block). All 8 chunk-blocks of a group hold the SAME
// resident x -> the last finisher (per-group counter) writes the group's
// outputs from registers. waves_per_eu(2,2) pins occupancy to exactly 2
// waves/EU: rounds 1-4 showed the allocator otherwise down-allocates VGPRs
// (44/48/64/84 observed) and parks x in AGPRs, re-reading it per code via
// v_accvgpr_read (~2x VALU issue: 40us issued vs 16us clean in round 4).
// With max=2 there is no occupancy reward below 256 VGPRs -> x stays in
// architectural VGPRs. KILL SIGNAL: VGPR_Count < 150 means parking persists.
//
// w dual-feed per code (round-4 loop body verbatim, absmax-0.0-verified):
// float4s 0..7 from LDS broadcast (8 ds_read_b128 ~36 cyc <= 42-cyc/CU
// budget at 8 waves/CU), float4s 8..15 via the scalar path (2
// s_load_dwordx16, streamed once -> no K$ reuse needed). ~170 VALU
// cyc/code-pair dominates both feeds.
//
// Swizzle: l = (bid&7)*64 + (bid>>3) (bijective). Under round-robin
// dispatch, XCD k gets l in [64k,64k+64) = groups [8k,8k+8) -> a group's 8
// chunk-blocks share one XCD (x HBM-fetched once; keys atomics intra-XCD).
//
// fp sequences are op-for-op the verified ones: dot loop = round-4 body
// (xa[2i] == (v2f){va[4i],va[4i+1]} by construction); sx = np tree in v2f
// form (A0..A3 lanes = r0..r7, same order, contract off, same final adds);
// d = fma(-2,dot,fl(sx+se[c])); strict < over ascending c; u64 key atomicMin
// across chunks; STE q = x + fl(w-x); loss in f64.
__global__ __launch_bounds__(256)
__attribute__((amdgpu_waves_per_eu(2, 2)))
void vq_fused(const float* __restrict__ x,
              const float* __restrict__ w,
              unsigned long long* __restrict__ keys,
              unsigned int* __restrict__ gcnt,     // [GROUPS] zeroed
              unsigned int* __restrict__ fincnt,   // [1] zeroed
              double* __restrict__ part,           // [GROUPS]
              float* __restrict__ outq,
              float* __restrict__ outidx,
              float* __restrict__ outloss) {
  __shared__ float wlo[CPC][32];    // low half (float4s 0..7) per code, 16KB
  __shared__ float se_lds[CPC];
  __shared__ double sp[4];
  __shared__ int sflag, finflag;

  const int bid = blockIdx.x;
  const int l = (bid & 7) * 64 + (bid >> 3);   // XCD-clustering, bijective
  const int group = l >> 3;                    // 0..63
  const int chunk = l & 7;                     // 0..7
  const int t = threadIdx.x;
  const int c0 = chunk * CPC;
  const float4* w4 = (const float4*)w;

  // Stage low halves: CPC*8 = 1024 float4s (16 KB), 4 per thread.
  {
    float4* dst = (float4*)&wlo[0][0];
#pragma unroll
    for (int k = 0; k < 4; ++k) {
      const int e = t + 256 * k;               // 0..1023 = c*8 + j4
      dst[e] = w4[(size_t)(c0 + (e >> 3)) * 16 + (e & 7)];
    }
  }
  // Per-code ||e||^2 for this chunk (exact verified tree; cold path).
  if (t < CPC) {
    float v[64];
    const float4* wr = (const float4*)(w + (size_t)(c0 + t) * DIM);
#pragma unroll
    for (int i = 0; i < 16; ++i) {
      float4 q = wr[i];
      v[4 * i + 0] = q.x; v[4 * i + 1] = q.y;
      v[4 * i + 2] = q.z; v[4 * i + 3] = q.w;
    }
    se_lds[t] = np_sumsq64(v);
  }

  // Two resident rows (128 floats) as v2f pairs: xa[2i],xa[2i+1] = float4 i.
  const int r0 = group * 512 + t;
  const int r1 = r0 + 256;
  v2f xa[32], xb[32];
  {
    const float4* xr0 = (const float4*)(x + (size_t)r0 * DIM);
    const float4* xr1 = (const float4*)(x + (size_t)r1 * DIM);
#pragma unroll
    for (int i = 0; i < 16; ++i) {
      float4 qa = xr0[i];
      xa[2 * i + 0] = (v2f){qa.x, qa.y};
      xa[2 * i + 1] = (v2f){qa.z, qa.w};
      float4 qb = xr1[i];
      xb[2 * i + 0] = (v2f){qb.x, qb.y};
      xb[2 * i + 1] = (v2f){qb.z, qb.w};
    }
  }
#pragma unroll
  for (int i = 0; i < 32; ++i) {
    asm volatile("" : "+v"(xa[i]));
    asm volatile("" : "+v"(xb[i]));
  }

  // sx via the verified np tree in v2f form: A0..A3 lanes == r0..r7,
  // accumulated in the same m-order, same final add tree, contract off.
  float sxa, sxb;
  {
#pragma clang fp contract(off)
    v2f A0 = xa[0] * xa[0], A1 = xa[1] * xa[1];
    v2f A2 = xa[2] * xa[2], A3 = xa[3] * xa[3];
    v2f B0 = xb[0] * xb[0], B1 = xb[1] * xb[1];
    v2f B2 = xb[2] * xb[2], B3 = xb[3] * xb[3];
#pragma unroll
    for (int m = 1; m < 8; ++m) {
      A0 += xa[4 * m + 0] * xa[4 * m + 0];
      A1 += xa[4 * m + 1] * xa[4 * m + 1];
      A2 += xa[4 * m + 2] * xa[4 * m + 2];
      A3 += xa[4 * m + 3] * xa[4 * m + 3];
      B0 += xb[4 * m + 0] * xb[4 * m + 0];
      B1 += xb[4 * m + 1] * xb[4 * m + 1];
      B2 += xb[4 * m + 2] * xb[4 * m + 2];
      B3 += xb[4 * m + 3] * xb[4 * m + 3];
    }
    sxa = ((A0.x + A0.y) + (A1.x + A1.y)) + ((A2.x + A2.y) + (A3.x + A3.y));
    sxb = ((B0.x + B0.y) + (B1.x + B1.y)) + ((B2.x + B2.y) + (B3.x + B3.y));
  }

  __syncthreads();

  float bda = __builtin_inff(); int bca = 0;
  float bdb = __builtin_inff(); int bcb = 0;

#pragma unroll 2
  for (int j = 0; j < CPC; ++j) {
    const int c = c0 + j;
    const float4* wl = (const float4*)&wlo[j][0];   // LDS broadcast
    const float4* wh = w4 + (size_t)c * 16;         // uniform -> s_load
    v2f a0 = (v2f){0.f, 0.f}, a1 = (v2f){0.f, 0.f};
    v2f a2 = (v2f){0.f, 0.f}, a3 = (v2f){0.f, 0.f};
    v2f b0 = (v2f){0.f, 0.f}, b1 = (v2f){0.f, 0.f};
    v2f b2 = (v2f){0.f, 0.f}, b3 = (v2f){0.f, 0.f};
#pragma unroll
    for (int i = 0; i < 8; i += 2) {                // float4s 0..7 (LDS)
      float4 t0 = wl[i];
      float4 t1 = wl[i + 1];
      a0 += (v2f){t0.x, t0.y} * xa[2 * i + 0];
      a1 += (v2f){t0.z, t0.w} * xa[2 * i + 1];
      a2 += (v2f){t1.x, t1.y} * xa[2 * i + 2];
      a3 += (v2f){t1.z, t1.w} * xa[2 * i + 3];
      b0 += (v2f){t0.x, t0.y} * xb[2 * i + 0];
      b1 += (v2f){t0.z, t0.w} * xb[2 * i + 1];
      b2 += (v2f){t1.x, t1.y} * xb[2 * i + 2];
      b3 += (v2f){t1.z, t1.w} * xb[2 * i + 3];
    }
#pragma unroll
    for (int i = 8; i < 16; i += 2) {               // float4s 8..15 (SMEM)
      float4 t0 = wh[i];
      float4 t1 = wh[i + 1];
      a0 += (v2f){t0.x, t0.y} * xa[2 * i + 0];
      a1 += (v2f){t0.z, t0.w} * xa[2 * i + 1];
      a2 += (v2f){t1.x, t1.y} * xa[2 * i + 2];
      a3 += (v2f){t1.z, t1.w} * xa[2 * i + 3];
      b0 += (v2f){t0.x, t0.y} * xb[2 * i + 0];
      b1 += (v2f){t0.z, t0.w} * xb[2 * i + 1];
      b2 += (v2f){t1.x, t1.y} * xb[2 * i + 2];
      b3 += (v2f){t1.z, t1.w} * xb[2 * i + 3];
    }
    {
      v2f s01 = a0 + a1;
      v2f s23 = a2 + a3;
      v2f s = s01 + s23;
      float dot = s.x + s.y;
      float d = fmaf(-2.0f, dot, sxa + se_lds[j]);
      if (d < bda) { bda = d; bca = c; }
    }
    {
      v2f s01 = b0 + b1;
      v2f s23 = b2 + b3;
      v2f s = s01 + s23;
      float dot = s.x + s.y;
      float d = fmaf(-2.0f, dot, sxb + se_lds[j]);
      if (d < bdb) { bdb = d; bcb = c; }
    }
  }

  atomicMin(&keys[r0], ((unsigned long long)__float_as_uint(bda) << 32) |
                           (unsigned long long)(unsigned)bca);
  atomicMin(&keys[r1], ((unsigned long long)__float_as_uint(bdb) << 32) |
                           (unsigned long long)(unsigned)bcb);

  // Group rendezvous: last of the 8 chunk-blocks becomes the finisher.
  __threadfence();
  if (t == 0) {
    unsigned int old = atomicAdd(&gcnt[group], 1u);
    sflag = (old == CHUNKS - 1) ? 1 : 0;
  }
  __syncthreads();
  if (!sflag) return;
  __threadfence();   // acquire: make all chunks' atomicMins visible

  // Finisher: outputs for the whole group from RESIDENT x (no x re-read).
  double acc = 0.0;
#pragma unroll
  for (int half = 0; half < 2; ++half) {
    const int row = half ? r1 : r0;
    const v2f* xv = half ? xb : xa;
    unsigned long long k = atomicMin(&keys[row], ~0ull);  // coherent read
    const int idx = (int)(unsigned int)(k & 0xFFFFFFFFull);
    outidx[row] = (float)idx;
    const float4* wr = (const float4*)(w + (size_t)idx * DIM);
    float4* oq = (float4*)(outq + (size_t)row * DIM);
#pragma unroll
    for (int i = 0; i < 16; ++i) {
      float4 wv = wr[i];
      const v2f xlo = xv[2 * i], xhi = xv[2 * i + 1];
      float tx = wv.x - xlo.x, ty = wv.y - xlo.y;
      float tz = wv.z - xhi.x, tw = wv.w - xhi.y;
      float4 q;
      q.x = xlo.x + tx; q.y = xlo.y + ty;   // ref STE: x + fl(w - x)
      q.z = xhi.x + tz; q.w = xhi.y + tw;
      oq[i] = q;
      acc += (double)tx * tx + (double)ty * ty + (double)tz * tz + (double)tw * tw;
    }
  }

#pragma unroll
  for (int s = 32; s > 0; s >>= 1) acc += __shfl_down(acc, s, 64);
  if ((t & 63) == 0) sp[t >> 6] = acc;
  __syncthreads();
  if (t == 0) {
    part[group] = (sp[0] + sp[1]) + (sp[2] + sp[3]);
    __threadfence();
    unsigned int old = atomicAdd(fincnt, 1u);
    finflag = (old == GROUPS - 1) ? 1 : 0;
  }
  __syncthreads();
  if (!finflag) return;
  __threadfence();

  // Last group's finisher: reduce 64 partials (parallel coherent reads).
  double a = (t < GROUPS) ? atomicAdd(&part[t], 0.0) : 0.0;
  if (t < 64) {
#pragma unroll
    for (int s = 32; s > 0; s >>= 1) a += __shfl_down(a, s, 64);
    if (t == 0) *outloss = 0.5f * (float)(a / (double)NELEM);
  }
}

extern "C" void kernel_launch(void* const* d_in, const int* in_sizes, int n_in,
                              void* d_out, int out_size, void* d_ws, size_t ws_size,
                              hipStream_t stream) {
  const float* x = (const float*)d_in[0];   // inputs (32,64,32,32) fp32
  const float* w = (const float*)d_in[1];   // weight (1024,64) fp32

  float* outq    = (float*)d_out;           // [0, 2097152)
  float* outidx  = outq + NELEM;            // [2097152, +32768)
  float* outloss = outidx + NROWS;          // [2129920]

  char* wsb = (char*)d_ws;
  unsigned long long* keys = (unsigned long long*)wsb;        // 256 KB
  unsigned int* gcnt = (unsigned int*)(wsb + 262144);          // 256 B
  unsigned int* fincnt = (unsigned int*)(wsb + 262144 + 256);  // 4 B
  double* part = (double*)(wsb + 263168);                      // 512 B

  hipMemsetAsync(keys, 0xFF, NROWS * sizeof(unsigned long long), stream);
  hipMemsetAsync(gcnt, 0, 512, stream);   // gcnt[64] + fincnt
  hipLaunchKernelGGL(vq_fused, dim3(GRID), dim3(256), 0, stream,
                     x, w, keys, gcnt, fincnt, part, outq, outidx, outloss);
}

// Round 6
// 127.310 us; speedup vs baseline: 1.4986x; 1.2551x over previous
//
#include <hip/hip_runtime.h>

#define NROWS  32768
#define DIM    64
#define KCODES 1024
#define NELEM  (NROWS * DIM)   // 2097152
#define CHUNKS 8
#define CPC    (KCODES / CHUNKS)   // 128 codes per chunk-block

typedef float v2f __attribute__((ext_vector_type(2)));

// numpy-style pairwise sum of squares for n=64 contiguous fp32 (contraction
// OFF so squared temps are not fused into adds; matches jnp.sum(w*w)).
// Verified absmax 0.0 in all prior rounds. Used for se (cold path).
__device__ __forceinline__ float np_sumsq64(const float v[64]) {
#pragma clang fp contract(off)
  float r0 = v[0] * v[0];
  float r1 = v[1] * v[1];
  float r2 = v[2] * v[2];
  float r3 = v[3] * v[3];
  float r4 = v[4] * v[4];
  float r5 = v[5] * v[5];
  float r6 = v[6] * v[6];
  float r7 = v[7] * v[7];
#pragma unroll
  for (int i = 8; i < 64; i += 8) {
    r0 += v[i + 0] * v[i + 0];
    r1 += v[i + 1] * v[i + 1];
    r2 += v[i + 2] * v[i + 2];
    r3 += v[i + 3] * v[i + 3];
    r4 += v[i + 4] * v[i + 4];
    r5 += v[i + 5] * v[i + 5];
    r6 += v[i + 6] * v[i + 6];
    r7 += v[i + 7] * v[i + 7];
  }
  return ((r0 + r1) + (r2 + r3)) + ((r4 + r5) + (r6 + r7));
}

// Init (grid 128x256): keys to +inf, per-code ||e||^2 (first 1024 threads).
// No x pass — vq_dist computes sx from its resident row for free.
__global__ __launch_bounds__(256) void vq_prep(const float* __restrict__ w,
                                               float* __restrict__ se,
                                               unsigned long long* __restrict__ keys) {
  const int t = blockIdx.x * 256 + threadIdx.x;  // 0..32767
  keys[t] = ~0ull;

  if (t < KCODES) {
    float v[64];
    const float4* wr = (const float4*)(w + (size_t)t * DIM);
#pragma unroll
    for (int i = 0; i < 16; ++i) {
      float4 q = wr[i];
      v[4 * i + 0] = q.x; v[4 * i + 1] = q.y;
      v[4 * i + 2] = q.z; v[4 * i + 3] = q.w;
    }
    se[t] = np_sumsq64(v);
  }
}

// Phase 2: distances + argmin. SESSION MODEL (closes all 6 rounds' counters):
// gfx950's register file is UNIFIED (no free AGPR stash); in every prior
// round the allocator kept <=116 arch regs and spilled/reloaded x through
// the VMEM path each code iteration: 16 dwordx4 wave-loads/code = 1KB of
// per-lane-distinct bytes each = 16cyc at L1's 64B/cyc return -> 256cyc of
// L1-return vs 152cyc VALU per code -> predicted VALUBusy 152/256=59%,
// round-1 measured 56%. FETCH never inflated because L1/L2 absorb reloads.
// Round-1's pin failed because launch_bounds(256,4) is only a MINIMUM: the
// allocator targeted 8 waves/EU (64-reg cap) and spilled the pinned values.
//
// Fix: M=1 (x=64 regs + ~30 working < 128) and amdgpu_waves_per_eu(4,4) —
// min=max=4 pins the budget at 128 VGPRs with zero occupancy reward for
// allocating less -> x genuinely resident; pin-before-loop makes the loaded
// values opaque (cannot be rematerialized from memory). SUCCESS SIGNAL:
// VGPR_Count ~100-128 and VALUBusy >=80%. w feed: scalar path only
// (4 s_load_dwordx16/code, wave-uniform; 1 per ~9.5cyc/CU at 16 waves/CU —
// trivial pipe load, latency covered by 4 independent waves/SIMD). No LDS:
// at 16 waves/CU the uniform ds_read_b128 return path (~4cyc each) would
// saturate (round-3 measured exactly that).
//
// Grid 1024 = 128 row-groups (256 rows) x 8 chunks (128 codes) = exactly
// 4 blocks/CU x 4 waves = 16 waves/CU, one clean residency round.
// XCD-bijective swizzle l=(bid&7)*128+(bid>>3): a group's 8 chunk-blocks
// land on one XCD (x HBM-fetched once; keys atomics intra-XCD).
//
// fp sequences op-for-op the verified ones: dot loop = round-1 body
// (absmax 0.0); sx = round-5's v2f np-tree (absmax 0.0; A0..A3 lanes =
// r0..r7, same order, contract off, same final combine);
// d = fma(-2,dot,fl(sx+se[c])); strict < over ascending c; u64 key
// (dist_bits<<32)|c atomicMin merges chunks with lowest-index tie-break.
__global__ __launch_bounds__(256)
__attribute__((amdgpu_waves_per_eu(4, 4)))
void vq_dist(const float* __restrict__ x,
             const float* __restrict__ w,
             const float* __restrict__ se,
             unsigned long long* __restrict__ keys) {
  const int bid = blockIdx.x;
  const int l = (bid & 7) * 128 + (bid >> 3);  // XCD-bijective (1024 = 8*128)
  const int group = l >> 3;                    // 0..127
  const int chunk = l & 7;                     // 0..7
  const int t = threadIdx.x;
  const int row = group * 256 + t;
  const int c0 = chunk * CPC;

  // Own row -> registers as v2f pairs (xv[2i],xv[2i+1] = float4 i).
  v2f xv[32];
  const float4* xr = (const float4*)(x + (size_t)row * DIM);
#pragma unroll
  for (int i = 0; i < 16; ++i) {
    float4 q = xr[i];
    xv[2 * i + 0] = (v2f){q.x, q.y};
    xv[2 * i + 1] = (v2f){q.z, q.w};
  }
#pragma unroll
  for (int i = 0; i < 32; ++i) asm volatile("" : "+v"(xv[i]));  // opaque pin

  // sx via the verified np tree in v2f form (round-5, absmax 0.0):
  // A0.x=r0, A0.y=r1, A1={r2,r3}, A2={r4,r5}, A3={r6,r7}.
  float sx;
  {
#pragma clang fp contract(off)
    v2f A0 = xv[0] * xv[0], A1 = xv[1] * xv[1];
    v2f A2 = xv[2] * xv[2], A3 = xv[3] * xv[3];
#pragma unroll
    for (int m = 1; m < 8; ++m) {
      A0 += xv[4 * m + 0] * xv[4 * m + 0];
      A1 += xv[4 * m + 1] * xv[4 * m + 1];
      A2 += xv[4 * m + 2] * xv[4 * m + 2];
      A3 += xv[4 * m + 3] * xv[4 * m + 3];
    }
    sx = ((A0.x + A0.y) + (A1.x + A1.y)) + ((A2.x + A2.y) + (A3.x + A3.y));
  }

  const float4* w4 = (const float4*)w;
  float bd = __builtin_inff();
  int bc = 0;

#pragma unroll 2
  for (int j = 0; j < CPC; ++j) {
    const int c = c0 + j;                      // wave-uniform -> scalar loads
    const float4* wr = w4 + (size_t)c * 16;
    v2f a0 = (v2f){0.f, 0.f}, a1 = (v2f){0.f, 0.f};
    v2f a2 = (v2f){0.f, 0.f}, a3 = (v2f){0.f, 0.f};
#pragma unroll
    for (int i = 0; i < 16; i += 2) {
      float4 t0 = wr[i];
      float4 t1 = wr[i + 1];
      a0 += (v2f){t0.x, t0.y} * xv[2 * i + 0];   // v_pk_fma_f32
      a1 += (v2f){t0.z, t0.w} * xv[2 * i + 1];
      a2 += (v2f){t1.x, t1.y} * xv[2 * i + 2];
      a3 += (v2f){t1.z, t1.w} * xv[2 * i + 3];
    }
    v2f s01 = a0 + a1;
    v2f s23 = a2 + a3;
    v2f s = s01 + s23;
    float dot = s.x + s.y;
    float d = fmaf(-2.0f, dot, sx + se[c]);
    if (d < bd) { bd = d; bc = c; }
  }

  unsigned long long key =
      ((unsigned long long)__float_as_uint(bd) << 32) | (unsigned long long)(unsigned)bc;
  atomicMin(&keys[row], key);
}

// Phase 3 (grid 1024x256, 32 rows/block — round-1 verbatim, part of the
// session-best 126us total): decode key -> index, indices (as float), STE
// output x + fl(w - x), fp64 partial -> part[b] plain store.
__global__ __launch_bounds__(256) void vq_out(const float* __restrict__ x,
                                              const float* __restrict__ w,
                                              const unsigned long long* __restrict__ keys,
                                              float* __restrict__ outq,
                                              float* __restrict__ outidx,
                                              double* __restrict__ part) {
  __shared__ int sidx[32];
  __shared__ double sp[4];
  const int b = blockIdx.x, t = threadIdx.x;

  if (t < 32) {
    const int row = b * 32 + t;
    unsigned long long k = keys[row];
    const int idx = (int)(unsigned int)(k & 0xFFFFFFFFull);
    outidx[row] = (float)idx;
    sidx[t] = idx;
  }
  __syncthreads();

  double acc = 0.0;
  const float4* x4 = (const float4*)x;
  float4* o4 = (float4*)outq;
#pragma unroll
  for (int i = 0; i < 2; ++i) {
    const int e = i * 256 + t;          // 0..511 float4s of this block's rows
    const int rl = e >> 4;              // local row (0..31)
    const int d4 = e & 15;              // float4 within the row
    const size_t gofs = ((size_t)b * 32 + rl) * 16 + d4;
    float4 xvv = x4[gofs];
    const float4* wr = (const float4*)(w + (size_t)sidx[rl] * DIM);
    float4 wv = wr[d4];
    float tx = wv.x - xvv.x, ty = wv.y - xvv.y;
    float tz = wv.z - xvv.z, tw = wv.w - xvv.w;
    float4 q;
    q.x = xvv.x + tx; q.y = xvv.y + ty;   // ref STE: x + fl(w - x)
    q.z = xvv.z + tz; q.w = xvv.w + tw;
    o4[gofs] = q;
    acc += (double)tx * tx + (double)ty * ty + (double)tz * tz + (double)tw * tw;
  }

#pragma unroll
  for (int s = 32; s > 0; s >>= 1) acc += __shfl_down(acc, s, 64);
  if ((t & 63) == 0) sp[t >> 6] = acc;
  __syncthreads();
  if (t == 0) part[b] = (sp[0] + sp[1]) + (sp[2] + sp[3]);
}

// Phase 4 (round-1 verbatim): reduce 1024 f64 partials, loss = 0.5 * mean.
__global__ __launch_bounds__(256) void vq_fin(const double* __restrict__ part,
                                              float* __restrict__ outloss) {
  __shared__ double sp[4];
  const int t = threadIdx.x;
  double a = (part[t] + part[t + 256]) + (part[t + 512] + part[t + 768]);
#pragma unroll
  for (int s = 32; s > 0; s >>= 1) a += __shfl_down(a, s, 64);
  if ((t & 63) == 0) sp[t >> 6] = a;
  __syncthreads();
  if (t == 0) {
    double total = (sp[0] + sp[1]) + (sp[2] + sp[3]);
    *outloss = 0.5f * (float)(total / (double)NELEM);
  }
}

extern "C" void kernel_launch(void* const* d_in, const int* in_sizes, int n_in,
                              void* d_out, int out_size, void* d_ws, size_t ws_size,
                              hipStream_t stream) {
  const float* x = (const float*)d_in[0];   // inputs (32,64,32,32) fp32
  const float* w = (const float*)d_in[1];   // weight (1024,64) fp32

  float* outq    = (float*)d_out;           // [0, 2097152)
  float* outidx  = outq + NELEM;            // [2097152, +32768)
  float* outloss = outidx + NROWS;          // [2129920]

  char* wsb = (char*)d_ws;
  float* se    = (float*)(wsb + 256);                               // 4 KB
  double* part = (double*)(wsb + 8192);                             // 8 KB
  unsigned long long* keys = (unsigned long long*)(wsb + 147456);   // 256 KB

  hipLaunchKernelGGL(vq_prep, dim3(128),  dim3(256), 0, stream, w, se, keys);
  hipLaunchKernelGGL(vq_dist, dim3(1024), dim3(256), 0, stream, x, w, se, keys);
  hipLaunchKernelGGL(vq_out,  dim3(1024), dim3(256), 0, stream, x, w, keys, outq, outidx, part);
  hipLaunchKernelGGL(vq_fin,  dim3(1),    dim3(256), 0, stream, part, outloss);
}